// Round 11
// baseline (72.251 us; speedup 1.0000x reference)
//
#include <hip/hip_runtime.h>
#include <math.h>

#define HW 3136
#define WDIM 56
#define HDIM 56
#define DDIM 16
#define CTOT 256
#define TILE_H 14
#define SROWS 16   // TILE_H + 2 halo rows
#define SW 60      // [pad0][data 1..56][pad57][unused 58,59] ; 240B row, 16B-aligned
#define WPL 6      // B window planes

typedef float v4f __attribute__((ext_vector_type(4)));
typedef unsigned int u32;
typedef u32 u32x2 __attribute__((ext_vector_type(2)));
typedef u32 u32x4 __attribute__((ext_vector_type(4)));
typedef __fp16 h2 __attribute__((ext_vector_type(2)));

__device__ __forceinline__ float sigmoidf_(float x) {
    return 1.0f / (1.0f + __expf(-x));
}

// pack {lo,hi} f32 -> f16x2 in a u32 (v_cvt_pkrtz_f16_f32)
__device__ __forceinline__ u32 packh2(float lo, float hi) {
    h2 r = __builtin_amdgcn_cvt_pkrtz(lo, hi);
    union { h2 h; u32 u; } c; c.h = r; return c.u;
}
__device__ __forceinline__ h2 ash2(u32 u) {
    union { u32 u; h2 h; } c; c.u = u; return c.h;
}

// Heterogeneous single kernel with XCD-slab swizzle.
//  xcd = bid&7, li = bid>>3, gb = (li/32)*8 + xcd, r = li%32.
//  32 blocks per gb-slab (16 A + 16 B), all on one XCD -> slab L2-resident.
//  r<16  -> type A: x0 plane mean->sigmoid->scale->store, regs only (dd=r).
//  r>=16 -> type B: 4 output planes, 6-plane LDS window conv on x1 (f16x2+fdot2).
__global__ __launch_bounds__(256, 7) void k_all(const float* __restrict__ x,
                                                const float* __restrict__ cw,
                                                const float* __restrict__ cb,
                                                const float* __restrict__ wconv,
                                                float* __restrict__ out) {
    __shared__ __align__(16) u32 ls[WPL][SROWS][SW];  // B: f16x2 {mean,max}
    __shared__ u32 wsh[27];                           // f16x2 {w_mean, w_max}
    __shared__ float reds[2][4];                      // A: wave partials

    const int bid = blockIdx.x;
    const int tid = threadIdx.x;
    const int xcd = bid & 7;
    const int li  = bid >> 3;                 // 0..1023
    const int gb  = ((li >> 5) << 3) + xcd;   // 0..255
    const int r   = li & 31;
    const int bb  = gb >> 6, g = gb & 63;
    const size_t cS = (size_t)DDIM * HW;

    if (r < 16) {
        // ================= TYPE A: x0 path =================
        const int dd = r;

        const float* p0 = x + ((size_t)bb * CTOT + g * 4 + 0) * cS + (size_t)dd * HW;
        const float* p1 = x + ((size_t)bb * CTOT + g * 4 + 1) * cS + (size_t)dd * HW;

        v4f a0 = __builtin_nontemporal_load((const v4f*)(p0 + 4 * (tid)));
        v4f a1 = __builtin_nontemporal_load((const v4f*)(p0 + 4 * (tid + 256)));
        v4f a2 = __builtin_nontemporal_load((const v4f*)(p0 + 4 * (tid + 512)));
        v4f b0 = __builtin_nontemporal_load((const v4f*)(p1 + 4 * (tid)));
        v4f b1 = __builtin_nontemporal_load((const v4f*)(p1 + 4 * (tid + 256)));
        v4f b2 = __builtin_nontemporal_load((const v4f*)(p1 + 4 * (tid + 512)));
        v4f a3 = (v4f){0.f, 0.f, 0.f, 0.f}, b3 = a3;
        if (tid < 16) {
            a3 = __builtin_nontemporal_load((const v4f*)(p0 + 4 * (tid + 768)));
            b3 = __builtin_nontemporal_load((const v4f*)(p1 + 4 * (tid + 768)));
        }

        float s0 = (a0[0]+a0[1]+a0[2]+a0[3]) + (a1[0]+a1[1]+a1[2]+a1[3])
                 + (a2[0]+a2[1]+a2[2]+a2[3]) + (a3[0]+a3[1]+a3[2]+a3[3]);
        float s1 = (b0[0]+b0[1]+b0[2]+b0[3]) + (b1[0]+b1[1]+b1[2]+b1[3])
                 + (b2[0]+b2[1]+b2[2]+b2[3]) + (b3[0]+b3[1]+b3[2]+b3[3]);
        #pragma unroll
        for (int off = 32; off > 0; off >>= 1) {
            s0 += __shfl_down(s0, off, 64);
            s1 += __shfl_down(s1, off, 64);
        }
        const int lane = tid & 63, wave = tid >> 6;
        if (lane == 0) { reds[0][wave] = s0; reds[1][wave] = s1; }
        __syncthreads();
        // all threads finalize redundantly (saves the second barrier)
        const float m0 = (reds[0][0]+reds[0][1]+reds[0][2]+reds[0][3]) * (1.0f / HW);
        const float m1 = (reds[1][0]+reds[1][1]+reds[1][2]+reds[1][3]) * (1.0f / HW);
        const float sc0 = sigmoidf_(cw[0 * DDIM + dd] * m0 + cb[0 * DDIM + dd]);
        const float sc1 = sigmoidf_(cw[1 * DDIM + dd] * m1 + cb[1 * DDIM + dd]);

        const int cs0 = g * 4 + 0, cs1 = g * 4 + 1;
        const int co0 = 2 * (cs0 & 127) + (cs0 >> 7);
        const int co1 = 2 * (cs1 & 127) + (cs1 >> 7);
        float* o0 = out + ((size_t)bb * CTOT + co0) * cS + (size_t)dd * HW;
        float* o1 = out + ((size_t)bb * CTOT + co1) * cS + (size_t)dd * HW;

        #pragma unroll
        for (int p = 0; p < 4; ++p) { a0[p] *= sc0; a1[p] *= sc0; a2[p] *= sc0; a3[p] *= sc0;
                                      b0[p] *= sc1; b1[p] *= sc1; b2[p] *= sc1; b3[p] *= sc1; }
        __builtin_nontemporal_store(a0, (v4f*)(o0 + 4 * (tid)));
        __builtin_nontemporal_store(a1, (v4f*)(o0 + 4 * (tid + 256)));
        __builtin_nontemporal_store(a2, (v4f*)(o0 + 4 * (tid + 512)));
        __builtin_nontemporal_store(b0, (v4f*)(o1 + 4 * (tid)));
        __builtin_nontemporal_store(b1, (v4f*)(o1 + 4 * (tid + 256)));
        __builtin_nontemporal_store(b2, (v4f*)(o1 + 4 * (tid + 512)));
        if (tid < 16) {
            __builtin_nontemporal_store(a3, (v4f*)(o0 + 4 * (tid + 768)));
            __builtin_nontemporal_store(b3, (v4f*)(o1 + 4 * (tid + 768)));
        }
        return;
    }

    // ================= TYPE B: x1 conv path (4 output planes) =================
    const int j   = r - 16;          // 0..15
    const int th  = j & 3;           // H tile
    const int dq  = j >> 2;          // 0..3
    const int dd0 = 4 * dq;          // output planes dd0..dd0+3
    const int r0  = th * TILE_H;

    if (tid < 27) wsh[tid] = packh2(wconv[tid], wconv[27 + tid]);
    // zero pad columns 0 and 57: 6 planes x 16 rows x 2 = 192
    if (tid < 192) {
        const int wp = tid / 32, rr = (tid >> 1) & 15;
        ls[wp][rr][(tid & 1) ? 57 : 0] = 0u;
    }

    const float* xb = x + ((size_t)bb * CTOT + g * 4) * cS;
    const float* pa = xb + 2 * cS;   // x1 channel 0
    const float* pb = xb + 3 * cS;   // x1 channel 1

    // stage 6 planes x 16 rows x 14 quads = 1344 items (5.25/thread)
    for (int it = tid; it < WPL * SROWS * 14; it += 256) {
        const int row = it / 14, qd = it - row * 14;
        const int wp = row >> 4, rr = row & 15;
        const int dz = dd0 + wp - 1;
        const int gr = r0 + rr - 1;
        const int gc0 = 4 * qd;
        u32 m0, m1, m2, m3;
        if (((unsigned)dz < DDIM) & ((unsigned)gr < HDIM)) {
            const size_t o = (size_t)dz * HW + gr * WDIM + gc0;
            const v4f a = *(const v4f*)(pa + o);
            const v4f b = *(const v4f*)(pb + o);
            m0 = packh2(0.5f * (a[0] + b[0]), fmaxf(a[0], b[0]));
            m1 = packh2(0.5f * (a[1] + b[1]), fmaxf(a[1], b[1]));
            m2 = packh2(0.5f * (a[2] + b[2]), fmaxf(a[2], b[2]));
            m3 = packh2(0.5f * (a[3] + b[3]), fmaxf(a[3], b[3]));
        } else {
            m0 = m1 = m2 = m3 = 0u;
        }
        u32* wr = &ls[wp][rr][1 + gc0];
        wr[0] = m0; wr[1] = m1; wr[2] = m2; wr[3] = m3;
    }
    __syncthreads();

    if (tid < TILE_H * 14) {         // 196 quad-threads, 4 planes each
        const int hh = tid / 14;
        const int ww = 4 * (tid - hh * 14);

        float acc[4][4] = {{0.f,0.f,0.f,0.f},{0.f,0.f,0.f,0.f},
                           {0.f,0.f,0.f,0.f},{0.f,0.f,0.f,0.f}};

        #pragma unroll
        for (int wp = 0; wp < WPL; ++wp) {
            #pragma unroll
            for (int kh = 0; kh < 3; ++kh) {
                const u32* rp = &ls[wp][hh + kh][ww];      // 16B-aligned
                const u32x4 q  = *(const u32x4*)rp;        // padded idx ww..ww+3
                const u32x2 q2 = *(const u32x2*)(rp + 4);  // ww+4, ww+5
                const u32 vv[6] = {q[0], q[1], q[2], q[3], q2[0], q2[1]};
                #pragma unroll
                for (int op = 0; op < 4; ++op) {
                    const int kd = wp - op;                // window plane -> tap
                    if (kd >= 0 && kd < 3) {
                        #pragma unroll
                        for (int kw = 0; kw < 3; ++kw) {
                            const h2 wv = ash2(wsh[kd * 9 + kh * 3 + kw]);
                            #pragma unroll
                            for (int p = 0; p < 4; ++p)
                                acc[op][p] = __builtin_amdgcn_fdot2(ash2(vv[p + kw]), wv, acc[op][p], false);
                        }
                    }
                }
            }
        }

        const int cs2 = g * 4 + 2, cs3 = g * 4 + 3;
        const int co2 = 2 * (cs2 & 127) + (cs2 >> 7);
        const int co3 = 2 * (cs3 & 127) + (cs3 >> 7);

        const int s = (r0 + hh) * WDIM + ww;   // 16B-aligned
        float* outb = out + (size_t)bb * CTOT * cS + s;
        #pragma unroll
        for (int op = 0; op < 4; ++op) {
            const size_t po = (size_t)(dd0 + op) * HW;
            const v4f v1a = *(const v4f*)(pa + po + s);   // L2-hot (same-XCD slab)
            const v4f v1b = *(const v4f*)(pb + po + s);
            v4f o2, o3;
            #pragma unroll
            for (int p = 0; p < 4; ++p) {
                const float sig = sigmoidf_(acc[op][p]);
                o2[p] = v1a[p] * sig;
                o3[p] = v1b[p] * sig;
            }
            __builtin_nontemporal_store(o2, (v4f*)(outb + (size_t)co2 * cS + po));
            __builtin_nontemporal_store(o3, (v4f*)(outb + (size_t)co3 * cS + po));
        }
    }
}

extern "C" void kernel_launch(void* const* d_in, const int* in_sizes, int n_in,
                              void* d_out, int out_size, void* d_ws, size_t ws_size,
                              hipStream_t stream) {
    const float* x     = (const float*)d_in[0];
    const float* cw    = (const float*)d_in[1];
    const float* cb    = (const float*)d_in[2];
    const float* wconv = (const float*)d_in[3];
    float* out = (float*)d_out;

    k_all<<<dim3(8192), 256, 0, stream>>>(x, cw, cb, wconv, out);
}

// Round 12
// 71.578 us; speedup vs baseline: 1.0094x; 1.0094x over previous
//
#include <hip/hip_runtime.h>
#include <math.h>

#define HW 3136
#define WDIM 56
#define HDIM 56
#define DDIM 16
#define CTOT 256
#define TILE_H 14
#define SROWS 16   // TILE_H + 2 halo rows
#define SW 60      // [pad0][data 1..56][pad57][unused 58,59] ; 240B row, 16B-aligned

typedef float v4f __attribute__((ext_vector_type(4)));
typedef unsigned int u32;
typedef u32 u32x2 __attribute__((ext_vector_type(2)));
typedef u32 u32x4 __attribute__((ext_vector_type(4)));
typedef __fp16 h2 __attribute__((ext_vector_type(2)));

__device__ __forceinline__ float sigmoidf_(float x) {
    return 1.0f / (1.0f + __expf(-x));
}

// pack {lo,hi} f32 -> f16x2 in a u32 (v_cvt_pkrtz_f16_f32)
__device__ __forceinline__ u32 packh2(float lo, float hi) {
    h2 r = __builtin_amdgcn_cvt_pkrtz(lo, hi);
    union { h2 h; u32 u; } c; c.h = r; return c.u;
}
__device__ __forceinline__ h2 ash2(u32 u) {
    union { u32 u; h2 h; } c; c.u = u; return c.h;
}

// Heterogeneous single kernel with XCD-slab swizzle (R10 structure):
//  xcd = bid&7, li = bid>>3, gb = (li/48)*8 + xcd, r = li%48.
//  All 48 blocks (16 type A + 32 type B) of one gb-slab land on one XCD,
//  adjacent in dispatch order -> slab (3.2 MB) stays L2-resident.
//  r<16  -> type A: x0 plane mean->sigmoid->scale->store, regs only (dd=r).
//  r>=16 -> type B: d-pair 4-plane LDS window conv on x1, f16x2+fdot2.
__global__ __launch_bounds__(256, 8) void k_all(const float* __restrict__ x,
                                                const float* __restrict__ cw,
                                                const float* __restrict__ cb,
                                                const float* __restrict__ wconv,
                                                float* __restrict__ out) {
    __shared__ __align__(16) u32 ls[4][SROWS][SW];  // B: f16x2 {mean,max}
    __shared__ u32 wsh[27];                         // f16x2 {w_mean, w_max}
    __shared__ float reds[2][4];                    // A: wave partials

    const int bid = blockIdx.x;
    const int tid = threadIdx.x;
    const int xcd = bid & 7;
    const int li  = bid >> 3;            // 0..1535
    const int gb  = ((li / 48) << 3) + xcd;   // 0..255
    const int r   = li % 48;
    const int bb  = gb >> 6, g = gb & 63;
    const size_t cS = (size_t)DDIM * HW;

    if (r < 16) {
        // ================= TYPE A: x0 path =================
        const int dd = r;

        const float* p0 = x + ((size_t)bb * CTOT + g * 4 + 0) * cS + (size_t)dd * HW;
        const float* p1 = x + ((size_t)bb * CTOT + g * 4 + 1) * cS + (size_t)dd * HW;

        v4f a0 = __builtin_nontemporal_load((const v4f*)(p0 + 4 * (tid)));
        v4f a1 = __builtin_nontemporal_load((const v4f*)(p0 + 4 * (tid + 256)));
        v4f a2 = __builtin_nontemporal_load((const v4f*)(p0 + 4 * (tid + 512)));
        v4f b0 = __builtin_nontemporal_load((const v4f*)(p1 + 4 * (tid)));
        v4f b1 = __builtin_nontemporal_load((const v4f*)(p1 + 4 * (tid + 256)));
        v4f b2 = __builtin_nontemporal_load((const v4f*)(p1 + 4 * (tid + 512)));
        v4f a3 = (v4f){0.f, 0.f, 0.f, 0.f}, b3 = a3;
        if (tid < 16) {
            a3 = __builtin_nontemporal_load((const v4f*)(p0 + 4 * (tid + 768)));
            b3 = __builtin_nontemporal_load((const v4f*)(p1 + 4 * (tid + 768)));
        }

        float s0 = (a0[0]+a0[1]+a0[2]+a0[3]) + (a1[0]+a1[1]+a1[2]+a1[3])
                 + (a2[0]+a2[1]+a2[2]+a2[3]) + (a3[0]+a3[1]+a3[2]+a3[3]);
        float s1 = (b0[0]+b0[1]+b0[2]+b0[3]) + (b1[0]+b1[1]+b1[2]+b1[3])
                 + (b2[0]+b2[1]+b2[2]+b2[3]) + (b3[0]+b3[1]+b3[2]+b3[3]);
        #pragma unroll
        for (int off = 32; off > 0; off >>= 1) {
            s0 += __shfl_down(s0, off, 64);
            s1 += __shfl_down(s1, off, 64);
        }
        const int lane = tid & 63, wave = tid >> 6;
        if (lane == 0) { reds[0][wave] = s0; reds[1][wave] = s1; }
        __syncthreads();
        // all threads finalize redundantly (no second barrier needed)
        const float m0 = (reds[0][0]+reds[0][1]+reds[0][2]+reds[0][3]) * (1.0f / HW);
        const float m1 = (reds[1][0]+reds[1][1]+reds[1][2]+reds[1][3]) * (1.0f / HW);
        const float sc0 = sigmoidf_(cw[0 * DDIM + dd] * m0 + cb[0 * DDIM + dd]);
        const float sc1 = sigmoidf_(cw[1 * DDIM + dd] * m1 + cb[1 * DDIM + dd]);

        const int cs0 = g * 4 + 0, cs1 = g * 4 + 1;
        const int co0 = 2 * (cs0 & 127) + (cs0 >> 7);
        const int co1 = 2 * (cs1 & 127) + (cs1 >> 7);
        float* o0 = out + ((size_t)bb * CTOT + co0) * cS + (size_t)dd * HW;
        float* o1 = out + ((size_t)bb * CTOT + co1) * cS + (size_t)dd * HW;

        #pragma unroll
        for (int p = 0; p < 4; ++p) { a0[p] *= sc0; a1[p] *= sc0; a2[p] *= sc0; a3[p] *= sc0;
                                      b0[p] *= sc1; b1[p] *= sc1; b2[p] *= sc1; b3[p] *= sc1; }
        __builtin_nontemporal_store(a0, (v4f*)(o0 + 4 * (tid)));
        __builtin_nontemporal_store(a1, (v4f*)(o0 + 4 * (tid + 256)));
        __builtin_nontemporal_store(a2, (v4f*)(o0 + 4 * (tid + 512)));
        __builtin_nontemporal_store(b0, (v4f*)(o1 + 4 * (tid)));
        __builtin_nontemporal_store(b1, (v4f*)(o1 + 4 * (tid + 256)));
        __builtin_nontemporal_store(b2, (v4f*)(o1 + 4 * (tid + 512)));
        if (tid < 16) {
            __builtin_nontemporal_store(a3, (v4f*)(o0 + 4 * (tid + 768)));
            __builtin_nontemporal_store(b3, (v4f*)(o1 + 4 * (tid + 768)));
        }
        return;
    }

    // ================= TYPE B: x1 conv path =================
    const int j   = r - 16;          // 0..31
    const int th  = j & 3;
    const int ddp = j >> 2;          // 0..7
    const int dd0 = 2 * ddp;
    const int r0  = th * TILE_H;

    if (tid < 27) wsh[tid] = packh2(wconv[tid], wconv[27 + tid]);
    // zero pad columns 0 and 57 (4 planes x 16 rows x 2) = 128
    if (tid < 128) {
        const int wp = tid >> 5, rr = (tid >> 1) & 15;
        ls[wp][rr][(tid & 1) ? 57 : 0] = 0u;
    }

    const float* xb = x + ((size_t)bb * CTOT + g * 4) * cS;
    const float* pa = xb + 2 * cS;   // x1 channel 0
    const float* pb = xb + 3 * cS;   // x1 channel 1

    // stage 4 planes x 16 rows x 14 quads = 896 items
    for (int it = tid; it < 4 * SROWS * 14; it += 256) {
        const int row = it / 14, qd = it - row * 14;
        const int wp = row >> 4, rr = row & 15;
        const int dz = dd0 + wp - 1;
        const int gr = r0 + rr - 1;
        const int gc0 = 4 * qd;
        u32 m0, m1, m2, m3;
        if (((unsigned)dz < DDIM) & ((unsigned)gr < HDIM)) {
            const size_t o = (size_t)dz * HW + gr * WDIM + gc0;
            const v4f a = *(const v4f*)(pa + o);
            const v4f b = *(const v4f*)(pb + o);
            m0 = packh2(0.5f * (a[0] + b[0]), fmaxf(a[0], b[0]));
            m1 = packh2(0.5f * (a[1] + b[1]), fmaxf(a[1], b[1]));
            m2 = packh2(0.5f * (a[2] + b[2]), fmaxf(a[2], b[2]));
            m3 = packh2(0.5f * (a[3] + b[3]), fmaxf(a[3], b[3]));
        } else {
            m0 = m1 = m2 = m3 = 0u;
        }
        u32* wr = &ls[wp][rr][1 + gc0];
        wr[0] = m0; wr[1] = m1; wr[2] = m2; wr[3] = m3;
    }
    __syncthreads();

    if (tid < TILE_H * 14) {         // 196 quad-threads, both planes
        const int hh = tid / 14;
        const int ww = 4 * (tid - hh * 14);

        float acc0[4] = {0.f, 0.f, 0.f, 0.f};
        float acc1[4] = {0.f, 0.f, 0.f, 0.f};

        #pragma unroll
        for (int wp = 0; wp < 4; ++wp) {
            #pragma unroll
            for (int kh = 0; kh < 3; ++kh) {
                const u32* rp = &ls[wp][hh + kh][ww];      // 16B-aligned
                const u32x4 q  = *(const u32x4*)rp;        // padded idx ww..ww+3
                const u32x2 q2 = *(const u32x2*)(rp + 4);  // ww+4, ww+5
                const u32 vv[6] = {q[0], q[1], q[2], q[3], q2[0], q2[1]};
                if (wp < 3) {
                    #pragma unroll
                    for (int kw = 0; kw < 3; ++kw) {
                        const h2 wv = ash2(wsh[wp * 9 + kh * 3 + kw]);
                        #pragma unroll
                        for (int p = 0; p < 4; ++p)
                            acc0[p] = __builtin_amdgcn_fdot2(ash2(vv[p + kw]), wv, acc0[p], false);
                    }
                }
                if (wp >= 1) {
                    #pragma unroll
                    for (int kw = 0; kw < 3; ++kw) {
                        const h2 wv = ash2(wsh[(wp - 1) * 9 + kh * 3 + kw]);
                        #pragma unroll
                        for (int p = 0; p < 4; ++p)
                            acc1[p] = __builtin_amdgcn_fdot2(ash2(vv[p + kw]), wv, acc1[p], false);
                    }
                }
            }
        }

        const int cs2 = g * 4 + 2, cs3 = g * 4 + 3;
        const int co2 = 2 * (cs2 & 127) + (cs2 >> 7);
        const int co3 = 2 * (cs3 & 127) + (cs3 >> 7);

        const int s = (r0 + hh) * WDIM + ww;   // 16B-aligned
        float* outb = out + (size_t)bb * CTOT * cS + s;
        #pragma unroll
        for (int pl = 0; pl < 2; ++pl) {
            const float* acc = pl ? acc1 : acc0;
            const size_t po = (size_t)(dd0 + pl) * HW;
            const v4f v1a = *(const v4f*)(pa + po + s);   // L2-hot (same-XCD slab)
            const v4f v1b = *(const v4f*)(pb + po + s);
            v4f o2, o3;
            #pragma unroll
            for (int p = 0; p < 4; ++p) {
                const float sig = sigmoidf_(acc[p]);
                o2[p] = v1a[p] * sig;
                o3[p] = v1b[p] * sig;
            }
            __builtin_nontemporal_store(o2, (v4f*)(outb + (size_t)co2 * cS + po));
            __builtin_nontemporal_store(o3, (v4f*)(outb + (size_t)co3 * cS + po));
        }
    }
}

extern "C" void kernel_launch(void* const* d_in, const int* in_sizes, int n_in,
                              void* d_out, int out_size, void* d_ws, size_t ws_size,
                              hipStream_t stream) {
    const float* x     = (const float*)d_in[0];
    const float* cw    = (const float*)d_in[1];
    const float* cb    = (const float*)d_in[2];
    const float* wconv = (const float*)d_in[3];
    float* out = (float*)d_out;

    k_all<<<dim3(12288), 256, 0, stream>>>(x, cw, cb, wconv, out);
}